// Round 8
// baseline (283.676 us; speedup 1.0000x reference)
//
#include <hip/hip_runtime.h>

#define N_ENT   50000
#define CH      128
#define N_EDGES 1600000
#define N_RELM1 10
#define NB      391           // ceil(N_ENT / 128) buckets of 128 heads
#define BCAP    4608          // real-entry bucket capacity (verified max fits)
#define BCAP_P  5120          // padded csr capacity: 4608 + 512 bins * 1 = 5120 (pad-to-2)
#define PART_BLOCKS 800
#define CHUNK   (N_EDGES / PART_BLOCKS)   // 2000 exactly
#define NRG     (N_ENT / 4)   // 12500 rowgroups of 4 heads
#define NKEY    512           // (rgl:5)(g2:2)(r:2) sort bins per bucket
#define EPS_N   1e-12f

#define RFL(x) __builtin_amdgcn_readfirstlane(x)

__device__ __forceinline__ unsigned int f2bf_bits(float f) {
    unsigned int x = __float_as_uint(f);
    return (x + 0x7FFFu + ((x >> 16) & 1u)) >> 16;   // RNE; values are finite
}

// Per block: ONE pass over its 2000 edges, stage entry+bucket in LDS,
// histogram, scan, LDS bin-scatter, coalesced write-out. Fused bf16 cvt.
// entry = tail(16) | rel(4)<<16 | hlow(7)<<20
__global__ __launch_bounds__(256) void gc_part_kernel(const int* __restrict__ head,
                                                      const int* __restrict__ tail,
                                                      const int* __restrict__ etyp,
                                                      int* __restrict__ barr,
                                                      int* __restrict__ pack,
                                                      const float* __restrict__ ent,
                                                      unsigned int* __restrict__ emb) {
    __shared__ int hist[512];                // NB bins padded
    __shared__ int boff_s[512];
    __shared__ int fctr[512];
    __shared__ int psum[256];
    __shared__ int stageE[CHUNK];            // raw entries (8 KB)
    __shared__ unsigned short stageB[CHUNK]; // bucket ids (4 KB)
    __shared__ int stage2[CHUNK];            // binned entries (8 KB)
    int tid = threadIdx.x, blk = blockIdx.x;
    for (int i = tid; i < 512; i += 256) { hist[i] = 0; fctr[i] = 0; }
    __syncthreads();
    int lo = blk * CHUNK;
    for (int i = tid; i < CHUNK; i += 256) {
        int e = lo + i;
        int h = head[e];
        int b = h >> 7;
        stageE[i] = (tail[e] & 0xFFFF) | ((etyp[e] - 1) << 16) | ((h & 127) << 20);
        stageB[i] = (unsigned short)b;
        atomicAdd(&hist[b], 1);
    }
    __syncthreads();
    // exclusive scan of 512 bins: 2 bins/thread + 256-ladder
    int a0 = hist[2 * tid], a1 = hist[2 * tid + 1];
    int s2 = a0 + a1;
    psum[tid] = s2;
    __syncthreads();
    for (int d = 1; d < 256; d <<= 1) {
        int t = (tid >= d) ? psum[tid - d] : 0;
        __syncthreads();
        psum[tid] += t;
        __syncthreads();
    }
    int excl = psum[tid] - s2;
    boff_s[2 * tid] = excl;
    boff_s[2 * tid + 1] = excl + a0;
    __syncthreads();
    for (int i = tid; i < CHUNK; i += 256) {
        int b = stageB[i];
        int pos = boff_s[b] + atomicAdd(&fctr[b], 1);
        stage2[pos] = stageE[i];
    }
    __syncthreads();
    for (int i = tid; i < CHUNK; i += 256) barr[lo + i] = stage2[i];
    for (int i = tid; i < NB; i += 256)
        pack[blk * NB + i] = (boff_s[i] << 8) | fctr[i];
    // fused cvt (independent streaming work)
    for (int i = blk * 256 + tid; i < N_ENT * (CH / 2); i += PART_BLOCKS * 256) {
        float2 v = *(const float2*)(ent + 2 * (size_t)i);
        emb[i] = f2bf_bits(v.x) | (f2bf_bits(v.y) << 16);
    }
}

// per bucket: gather the 800 part-block windows to LDS, then sort entries by
// key = (rowgroup:5 | g2:2 | row:2), g2 = tail>>14 (4 supergroups -> ~4 MB
// chip-wide gather window, L2-resident). Every (g2,row) run is PADDED TO A
// MULTIPLE OF 2 (avg +0.5 dummy/bin vs +3.5 at pad-to-8) with dummy entries
// (rel=15 -> zero weight), so each edge PAIR maps to exactly one row. Emits:
//   deg_arr[h]       true in-degree (mean divisor)
//   cpk[rg*4+r]      4 packed bytes: PAIR count per g2 for row r
//   rg_off[rg]       csr start (even)
//   csr              padded entries: tail | rel<<16
__global__ __launch_bounds__(1024) void gc_place_kernel(const int* __restrict__ barr,
                                                        const int* __restrict__ pack,
                                                        int* __restrict__ deg_arr,
                                                        int* __restrict__ rg_off,
                                                        int* __restrict__ cpk,
                                                        int* __restrict__ csr) {
    __shared__ int ent_s[BCAP];
    __shared__ int psum[1024];
    __shared__ int kcnt[NKEY];
    __shared__ int kctr[NKEY];
    __shared__ int kbase[NKEY];
    int b = blockIdx.x, tid = threadIdx.x;
    if (tid < NKEY) { kcnt[tid] = 0; kctr[tid] = 0; }
    int c = 0, o = 0;
    if (tid < PART_BLOCKS) {
        int pk = pack[tid * NB + b];
        c = pk & 255;
        o = pk >> 8;
    }
    psum[tid] = c;
    __syncthreads();
    for (int d = 1; d < 1024; d <<= 1) {
        int t = (tid >= d) ? psum[tid - d] : 0;
        __syncthreads();
        psum[tid] += t;
        __syncthreads();
    }
    int my_off = psum[tid] - c;
    int n = psum[1023];
    const int* src = barr + tid * CHUNK + o;
    for (int k = 0; k < c; ++k) ent_s[my_off + k] = src[k];
    __syncthreads();
    // histogram over 512 keys
    for (int i = tid; i < n; i += 1024) {
        int e = ent_s[i];
        int hl = (e >> 20) & 127;
        int key = ((hl >> 2) << 4) | (((e >> 14) & 3) << 2) | (hl & 3);
        atomicAdd(&kcnt[key], 1);
    }
    __syncthreads();
    // per-row degree + packed per-g2 PAIR counts (tid<128: rgl=tid>>2, r=tid&3)
    if (tid < 128) {
        int rgl = tid >> 2, r = tid & 3;
        int base = (rgl << 4) | r;
        int c0 = kcnt[base], c1 = kcnt[base + 4], c2 = kcnt[base + 8], c3 = kcnt[base + 12];
        int h = (b << 7) + tid;
        if (h < N_ENT) {
            deg_arr[h] = c0 + c1 + c2 + c3;
            cpk[(((b << 5) + rgl) << 2) + r] =
                ((c0 + 1) >> 1) | (((c1 + 1) >> 1) << 8) |
                (((c2 + 1) >> 1) << 16) | (((c3 + 1) >> 1) << 24);
        }
    }
    // pad-to-2 exclusive scan over 512 bins (2 bins/thread on first 256 threads)
    int a0 = 0, a1 = 0, s2 = 0;
    if (tid < 256) {
        a0 = (kcnt[2 * tid] + 1) & ~1;
        a1 = (kcnt[2 * tid + 1] + 1) & ~1;
        s2 = a0 + a1;
        psum[tid] = s2;
    }
    __syncthreads();
    for (int d = 1; d < 256; d <<= 1) {
        int t = (tid < 256 && tid >= d) ? psum[tid - d] : 0;
        __syncthreads();
        if (tid < 256) psum[tid] += t;
        __syncthreads();
    }
    if (tid < 256) {
        int excl = psum[tid] - s2;
        kbase[2 * tid] = excl;
        kbase[2 * tid + 1] = excl + a0;
    }
    __syncthreads();
    int lo = b * BCAP_P;
    if (tid < 32) {
        int grg = (b << 5) + tid;
        if (grg < NRG) rg_off[grg] = lo + kbase[tid << 4];
    }
    // scatter real entries (strip hlow bits; keep tail | rel<<16)
    for (int i = tid; i < n; i += 1024) {
        int e = ent_s[i];
        int hl = (e >> 20) & 127;
        int key = ((hl >> 2) << 4) | (((e >> 14) & 3) << 2) | (hl & 3);
        int pos = lo + kbase[key] + atomicAdd(&kctr[key], 1);
        csr[pos] = e & 0xFFFFF;
    }
    __syncthreads();
    // pad fill: at most ONE dummy per bin (rel 15 -> zero weight, tail 0)
    if (tid < NKEY) {
        int cc = kcnt[tid];
        if (cc & 1) csr[lo + kbase[tid] + cc] = 15 << 16;
    }
}

// one wave64 per 4 rows, 12500 waves (32 waves/CU cap). PAIR SCHEME: lanes
// 0-31 process edge 2k, lanes 32-63 edge 2k+1 (same row, runs padded to 2).
// Each lane covers 4 channels: one uint2 gather (8B/lane) + one ds_read_b128
// weight read per pair. Meta is a per-lane dword load (each half reads its
// own edge's entry; L1 broadcast) -> no RFL, no cndmask in the hot loop.
// Per edge: 7 VALU + 1 VMEM + 0.5 LDS (was 11/1/1), and pad-to-2 cuts total
// slots 2.35M -> 1.71M. Accumulators are half-split; epilogue does 4
// shfl_xor(32) fix-ups per row and stores from lanes<32.
__global__ __launch_bounds__(256, 8) void gc_hop_kernel(
        const unsigned int* __restrict__ src,     // bf16x2 per uint
        const int* __restrict__ deg_arr,
        const int* __restrict__ rg_off,
        const int* __restrict__ cpk,
        const int* __restrict__ csr,
        const float* __restrict__ wt,
        unsigned int* __restrict__ dst,
        float* __restrict__ res,
        const float* __restrict__ ent,
        const unsigned int* __restrict__ yprev,
        int mode) {
    __shared__ float wt_s[16 * CH];   // rows 10..15 ZERO (dummy rel=15 -> 0)
    for (int i = threadIdx.x; i < 16 * CH; i += 256)
        wt_s[i] = (i < N_RELM1 * CH) ? wt[i] : 0.f;
    __syncthreads();

    int wave = threadIdx.x >> 6, lane = threadIdx.x & 63;
    int rg = RFL(blockIdx.x * 4 + wave);
    if (rg >= NRG) return;    // no barriers below

    int4 dd = ((const int4*)deg_arr)[rg];
    int4 cc = ((const int4*)cpk)[rg];
    int segv = rg_off[rg];

    int D0 = RFL(dd.x), D1 = RFL(dd.y), D2 = RFL(dd.z), D3 = RFL(dd.w);
    int C0 = RFL(cc.x), C1 = RFL(cc.y), C2 = RFL(cc.z), C3 = RFL(cc.w);
    int seg = RFL(segv);

    int l31 = lane & 31;
    int half = lane >> 5;
    const char* srcb = (const char*)src;
    int goff = l31 * 8;                       // byte offset within a 256B row
    const float* wrow = wt_s + l31 * 4;       // + rel*CH floats
    int mofs = (seg + half) * 4;              // per-lane meta byte offset (+8/pair)
    const char* csrb = (const char*)csr;

    // acc[row][4 channels]: 16 named VGPRs; halves hold even/odd-edge partials
    float a00 = 0.f, a01 = 0.f, a02 = 0.f, a03 = 0.f;
    float a10 = 0.f, a11 = 0.f, a12 = 0.f, a13 = 0.f;
    float a20 = 0.f, a21 = 0.f, a22 = 0.f, a23 = 0.f;
    float a30 = 0.f, a31 = 0.f, a32 = 0.f, a33 = 0.f;

#define PAIR(A0, A1, A2, A3) { \
    int m_ = *(const int*)(csrb + mofs); mofs += 8; \
    uint2 v_ = *(const uint2*)(srcb + (unsigned)(m_ & 0xFFFF) * 256u + goff); \
    float4 w_ = *(const float4*)(wrow + ((m_ >> 16) & 15) * CH); \
    A0 = fmaf(__uint_as_float(v_.x << 16), w_.x, A0); \
    A1 = fmaf(__uint_as_float(v_.x & 0xFFFF0000u), w_.y, A1); \
    A2 = fmaf(__uint_as_float(v_.y << 16), w_.z, A2); \
    A3 = fmaf(__uint_as_float(v_.y & 0xFFFF0000u), w_.w, A3); }

#define RUN(A0, A1, A2, A3, Cr) { \
    int np_ = (Cr >> sh) & 255; \
    int k_ = 0; \
    for (; k_ + 2 <= np_; k_ += 2) { PAIR(A0, A1, A2, A3) PAIR(A0, A1, A2, A3) } \
    if (k_ < np_) { PAIR(A0, A1, A2, A3) } }

    for (int g2 = 0; g2 < 4; ++g2) {
        int sh = g2 << 3;
        RUN(a00, a01, a02, a03, C0)
        RUN(a10, a11, a12, a13, C1)
        RUN(a20, a21, a22, a23, C2)
        RUN(a30, a31, a32, a33, C3)
    }
#undef RUN
#undef PAIR

#define ROWOUT(r, A0, A1, A2, A3, Dr) { \
        int row = (rg << 2) + r; \
        A0 += __shfl_xor(A0, 32, 64); \
        A1 += __shfl_xor(A1, 32, 64); \
        A2 += __shfl_xor(A2, 32, 64); \
        A3 += __shfl_xor(A3, 32, 64); \
        float invd = 1.0f / fmaxf((float)Dr, 1.0f); \
        float x0 = A0 * invd, x1 = A1 * invd, x2 = A2 * invd, x3 = A3 * invd; \
        float s = x0 * x0 + x1 * x1 + x2 * x2 + x3 * x3; \
        _Pragma("unroll") \
        for (int o = 32; o; o >>= 1) s += __shfl_xor(s, o, 64); \
        s *= 0.5f;   /* halves are duplicates after fix-up */ \
        float inv = 1.0f / fmaxf(sqrtf(s), EPS_N); \
        float y0 = x0 * inv, y1 = x1 * inv, y2 = x2 * inv, y3 = x3 * inv; \
        if (lane < 32) { \
            int idx = (row << 5) + l31; \
            if (mode == 0) { \
                uint2 u; \
                u.x = f2bf_bits(y0) | (f2bf_bits(y1) << 16); \
                u.y = f2bf_bits(y2) | (f2bf_bits(y3) << 16); \
                ((uint2*)dst)[idx] = u; \
            } else { \
                uint2 p1 = ((const uint2*)yprev)[idx]; \
                uint2 p2 = ((const uint2*)src)[idx]; \
                float4 e = ((const float4*)ent)[idx]; \
                float4 o2; \
                o2.x = e.x + __uint_as_float(p1.x << 16) \
                           + __uint_as_float(p2.x << 16) + y0; \
                o2.y = e.y + __uint_as_float(p1.x & 0xFFFF0000u) \
                           + __uint_as_float(p2.x & 0xFFFF0000u) + y1; \
                o2.z = e.z + __uint_as_float(p1.y << 16) \
                           + __uint_as_float(p2.y << 16) + y2; \
                o2.w = e.w + __uint_as_float(p1.y & 0xFFFF0000u) \
                           + __uint_as_float(p2.y & 0xFFFF0000u) + y3; \
                ((float4*)res)[idx] = o2; \
            } \
        } }

    ROWOUT(0, a00, a01, a02, a03, D0);
    ROWOUT(1, a10, a11, a12, a13, D1);
    ROWOUT(2, a20, a21, a22, a23, D2);
    ROWOUT(3, a30, a31, a32, a33, D3);
#undef ROWOUT
}

extern "C" void kernel_launch(void* const* d_in, const int* in_sizes, int n_in,
                              void* d_out, int out_size, void* d_ws, size_t ws_size,
                              hipStream_t stream) {
    const float* ent  = (const float*)d_in[0];
    const int*   eidx = (const int*)d_in[1];   // [2, E]: head row 0, tail row 1
    const int*   etyp = (const int*)d_in[2];
    const float* wt   = (const float*)d_in[3];
    float*       res  = (float*)d_out;

    const int* head = eidx;
    const int* tail = eidx + N_EDGES;

    // workspace layout (~34 MB). barr+pack ALIAS embB (dead until hop1).
    unsigned int* embA = (unsigned int*)d_ws;                 // 12.8 MB
    unsigned int* embB = embA + (size_t)N_ENT * 64;           // 12.8 MB
    int* barr = (int*)embB;                                   // alias (6.4 MB)
    int* pack = (int*)embB + N_EDGES;                         // alias (1.25 MB)
    int* csr     = (int*)(embB + (size_t)N_ENT * 64);         // 8.0 MB (NB*BCAP_P)
    int* deg_arr = csr + (size_t)NB * BCAP_P;                 // 0.2 MB
    int* rg_off  = deg_arr + N_ENT;                           // NRG (pad 12544)
    int* cpk     = rg_off + 12544;                            // 0.2 MB

    gc_part_kernel<<<PART_BLOCKS, 256, 0, stream>>>(head, tail, etyp, barr, pack,
                                                    ent, embA);
    gc_place_kernel<<<NB, 1024, 0, stream>>>(barr, pack, deg_arr, rg_off, cpk, csr);

    const int hop_grid = NRG / 4;   // 3125 blocks of 4 waves = 12500 waves
    // hop1: y1 -> embB
    gc_hop_kernel<<<hop_grid, 256, 0, stream>>>(embA, deg_arr, rg_off, cpk, csr,
                                                wt, embB, res, ent, embB, 0);
    // hop2: y2 -> embA
    gc_hop_kernel<<<hop_grid, 256, 0, stream>>>(embB, deg_arr, rg_off, cpk, csr,
                                                wt, embA, res, ent, embB, 0);
    // hop3: gathers from embA (y2), reads embB (y1) + ent, writes res only
    gc_hop_kernel<<<hop_grid, 256, 0, stream>>>(embA, deg_arr, rg_off, cpk, csr,
                                                wt, embB, res, ent, embB, 1);
}